// Round 1
// baseline (415.779 us; speedup 1.0000x reference)
//
#include <hip/hip_runtime.h>

// LeNet forward, BATCH=4096, all-fp32. trunc = zero low 13 mantissa bits.
// ws layout (floats): p1[4096*2880] | p2[4096*800] | h1[4096*500]  (~69 MB)

__device__ __forceinline__ float trunc13(float v) {
    return __int_as_float(__float_as_int(v) & (int)0xFFFFE000u);
}

// ---------------------------------------------------------------------------
// K1: conv1 (1->20, 5x5, VALID) + bias + trunc + relu + 2x2 maxpool
// x:[4096,1,28,28]  w1:[20,25]  b1:[20]  ->  p1:[4096,20,12,12]
// Thread per (image, pooled pos). 6x6 input patch in regs, all 20 oc looped.
// ---------------------------------------------------------------------------
__global__ __launch_bounds__(256) void k_conv1(const float* __restrict__ x,
                                               const float* __restrict__ w1,
                                               const float* __restrict__ b1,
                                               float* __restrict__ p1) {
    __shared__ float wsm[500];
    __shared__ float bsm[20];
    int tid = threadIdx.x;
    for (int t = tid; t < 500; t += 256) wsm[t] = w1[t];
    if (tid < 20) bsm[tid] = b1[tid];
    __syncthreads();

    int gid = blockIdx.x * 256 + tid;   // 4096*144 = 589824 = 2304*256 exact
    int b   = gid / 144;
    int pos = gid % 144;
    int py = pos / 12, px = pos % 12;
    const float* img = x + (size_t)b * 784;

    float patch[36];
#pragma unroll
    for (int r = 0; r < 6; ++r)
#pragma unroll
        for (int c = 0; c < 6; ++c)
            patch[r * 6 + c] = img[(2 * py + r) * 28 + 2 * px + c];

    float* outp = p1 + (size_t)b * 2880 + pos;
    for (int oc = 0; oc < 20; ++oc) {
        float bias = bsm[oc];
        float s00 = bias, s01 = bias, s10 = bias, s11 = bias;
        const float* w = &wsm[oc * 25];
#pragma unroll
        for (int ky = 0; ky < 5; ++ky)
#pragma unroll
            for (int kx = 0; kx < 5; ++kx) {
                float wv = w[ky * 5 + kx];
                s00 += patch[ky * 6 + kx] * wv;
                s01 += patch[ky * 6 + kx + 1] * wv;
                s10 += patch[(ky + 1) * 6 + kx] * wv;
                s11 += patch[(ky + 1) * 6 + kx + 1] * wv;
            }
        float m = fmaxf(fmaxf(fmaxf(trunc13(s00), 0.f), fmaxf(trunc13(s01), 0.f)),
                        fmaxf(fmaxf(trunc13(s10), 0.f), fmaxf(trunc13(s11), 0.f)));
        outp[oc * 144] = m;
    }
}

// ---------------------------------------------------------------------------
// K2: conv2 (20->50, 5x5) + bias + trunc + relu + 2x2 maxpool
// p1:[4096,20,12,12]  w2:[50,20,25]  b2:[50]  ->  p2:[4096,800]  (NCHW flat)
// Block per image: input in LDS; thread per (oc,pooled pos); per-ic 6x6 patch
// in regs so each LDS value feeds ~2.8 FMA, weights via L1 (hot, 100 KB).
// ---------------------------------------------------------------------------
__global__ __launch_bounds__(128) void k_conv2(const float* __restrict__ p1,
                                               const float* __restrict__ w2,
                                               const float* __restrict__ b2,
                                               float* __restrict__ p2) {
    __shared__ float in0[2880];
    int b = blockIdx.x;
    int tid = threadIdx.x;
    for (int t = tid; t < 2880; t += 128) in0[t] = p1[(size_t)b * 2880 + t];
    __syncthreads();

    for (int o = tid; o < 800; o += 128) {
        int oc = o >> 4;
        int pos = o & 15;
        int py = pos >> 2, px = pos & 3;
        float bias = b2[oc];
        float s00 = bias, s01 = bias, s10 = bias, s11 = bias;
        const float* wbase = w2 + oc * 500;
        for (int ic = 0; ic < 20; ++ic) {
            float patch[36];
            const float* ip = &in0[ic * 144 + 2 * py * 12 + 2 * px];
#pragma unroll
            for (int r = 0; r < 6; ++r)
#pragma unroll
                for (int c = 0; c < 6; ++c)
                    patch[r * 6 + c] = ip[r * 12 + c];
            const float* w = wbase + ic * 25;
#pragma unroll
            for (int ky = 0; ky < 5; ++ky)
#pragma unroll
                for (int kx = 0; kx < 5; ++kx) {
                    float wv = w[ky * 5 + kx];
                    s00 += patch[ky * 6 + kx] * wv;
                    s01 += patch[ky * 6 + kx + 1] * wv;
                    s10 += patch[(ky + 1) * 6 + kx] * wv;
                    s11 += patch[(ky + 1) * 6 + kx + 1] * wv;
                }
        }
        float m = fmaxf(fmaxf(fmaxf(trunc13(s00), 0.f), fmaxf(trunc13(s01), 0.f)),
                        fmaxf(fmaxf(trunc13(s10), 0.f), fmaxf(trunc13(s11), 0.f)));
        p2[(size_t)b * 800 + o] = m;
    }
}

// ---------------------------------------------------------------------------
// K3: fc1  H = relu(trunc(A @ W^T + b))   A:[4096,800] W:[500,800] -> [4096,500]
// 64x64 block tile, BK=16, 4x4 micro-tile, k-major LDS tiles (stride 68 for
// 16B alignment + conflict spread).
// ---------------------------------------------------------------------------
__global__ __launch_bounds__(256) void k_fc1(const float* __restrict__ A,
                                             const float* __restrict__ W,
                                             const float* __restrict__ bias,
                                             float* __restrict__ H) {
    __shared__ __align__(16) float As[16][68];
    __shared__ __align__(16) float Ws[16][68];
    int tid = threadIdx.x;
    int tx = tid & 15;    // k index within step
    int ty = tid >> 4;    // 0..15
    int i0 = blockIdx.x * 64;
    int n0 = blockIdx.y * 64;
    int tm = tid & 15;    // output row group
    int tn = tid >> 4;    // output col group
    float acc[4][4] = {};

    for (int k0 = 0; k0 < 800; k0 += 16) {
#pragma unroll
        for (int q = 0; q < 4; ++q) {
            int row = ty + 16 * q;
            As[tx][row] = A[(size_t)(i0 + row) * 800 + k0 + tx];
            int n = n0 + row;
            Ws[tx][row] = (n < 500) ? W[(size_t)n * 800 + k0 + tx] : 0.f;
        }
        __syncthreads();
#pragma unroll
        for (int k = 0; k < 16; ++k) {
            float4 a = *reinterpret_cast<const float4*>(&As[k][tm * 4]);
            float4 w = *reinterpret_cast<const float4*>(&Ws[k][tn * 4]);
            float av[4] = {a.x, a.y, a.z, a.w};
            float wv[4] = {w.x, w.y, w.z, w.w};
#pragma unroll
            for (int r = 0; r < 4; ++r)
#pragma unroll
                for (int c = 0; c < 4; ++c)
                    acc[r][c] += av[r] * wv[c];
        }
        __syncthreads();
    }

#pragma unroll
    for (int r = 0; r < 4; ++r) {
        int i = i0 + tm * 4 + r;
#pragma unroll
        for (int c = 0; c < 4; ++c) {
            int n = n0 + tn * 4 + c;
            if (n < 500)
                H[(size_t)i * 500 + n] = fmaxf(trunc13(acc[r][c] + bias[n]), 0.f);
        }
    }
}

// ---------------------------------------------------------------------------
// K4: fc2 (500->10) + bias + trunc + log_softmax.  One wave (64 lanes) per row.
// ---------------------------------------------------------------------------
__global__ __launch_bounds__(256) void k_fc2(const float* __restrict__ H,
                                             const float* __restrict__ W,
                                             const float* __restrict__ bias,
                                             float* __restrict__ out) {
    int wave = threadIdx.x >> 6;
    int lane = threadIdx.x & 63;
    int i = blockIdx.x * 4 + wave;
    const float* hrow = H + (size_t)i * 500;

    float p[10];
#pragma unroll
    for (int j = 0; j < 10; ++j) p[j] = 0.f;
    for (int k = lane; k < 500; k += 64) {
        float h = hrow[k];
#pragma unroll
        for (int j = 0; j < 10; ++j) p[j] += h * W[j * 500 + k];
    }
#pragma unroll
    for (int j = 0; j < 10; ++j)
#pragma unroll
        for (int off = 32; off; off >>= 1) p[j] += __shfl_xor(p[j], off, 64);

    if (lane == 0) {
        float z[10], m = -1e30f;
#pragma unroll
        for (int j = 0; j < 10; ++j) {
            z[j] = trunc13(p[j] + bias[j]);
            m = fmaxf(m, z[j]);
        }
        float s = 0.f;
#pragma unroll
        for (int j = 0; j < 10; ++j) s += expf(z[j] - m);
        float lse = m + logf(s);
#pragma unroll
        for (int j = 0; j < 10; ++j) out[(size_t)i * 10 + j] = z[j] - lse;
    }
}

// ---------------------------------------------------------------------------
extern "C" void kernel_launch(void* const* d_in, const int* in_sizes, int n_in,
                              void* d_out, int out_size, void* d_ws, size_t ws_size,
                              hipStream_t stream) {
    const float* x   = (const float*)d_in[0];
    const float* w1  = (const float*)d_in[1];
    const float* b1  = (const float*)d_in[2];
    const float* w2  = (const float*)d_in[3];
    const float* b2  = (const float*)d_in[4];
    const float* wf1 = (const float*)d_in[5];
    const float* bf1 = (const float*)d_in[6];
    const float* wf2 = (const float*)d_in[7];
    const float* bf2 = (const float*)d_in[8];
    float* out = (float*)d_out;

    float* p1 = (float*)d_ws;                        // 4096*2880
    float* p2 = p1 + (size_t)4096 * 2880;            // 4096*800
    float* h1 = p2 + (size_t)4096 * 800;             // 4096*500

    k_conv1<<<2304, 256, 0, stream>>>(x, w1, b1, p1);
    k_conv2<<<4096, 128, 0, stream>>>(p1, w2, b2, p2);
    dim3 g3(64, 8);
    k_fc1<<<g3, 256, 0, stream>>>(p2, wf1, bf1, h1);
    k_fc2<<<1024, 256, 0, stream>>>(h1, wf2, bf2, out);
}

// Round 2
// 376.067 us; speedup vs baseline: 1.1056x; 1.1056x over previous
//
#include <hip/hip_runtime.h>

// LeNet forward, BATCH=4096, all-fp32. trunc = zero low 13 mantissa bits.
// ws layout (floats): p1[4096*2880] | p2[4096*800] | h1[4096*500]  (~69 MB)

__device__ __forceinline__ float trunc13(float v) {
    return __int_as_float(__float_as_int(v) & (int)0xFFFFE000u);
}

// ---------------------------------------------------------------------------
// K1: conv1 (1->20, 5x5, VALID) + bias + trunc + relu + 2x2 maxpool
// x:[4096,1,28,28]  w1:[20,25]  b1:[20]  ->  p1:[4096,20,12,12]
// ---------------------------------------------------------------------------
__global__ __launch_bounds__(256) void k_conv1(const float* __restrict__ x,
                                               const float* __restrict__ w1,
                                               const float* __restrict__ b1,
                                               float* __restrict__ p1) {
    __shared__ float wsm[500];
    __shared__ float bsm[20];
    int tid = threadIdx.x;
    for (int t = tid; t < 500; t += 256) wsm[t] = w1[t];
    if (tid < 20) bsm[tid] = b1[tid];
    __syncthreads();

    int gid = blockIdx.x * 256 + tid;   // 4096*144 = 589824 = 2304*256 exact
    int b   = gid / 144;
    int pos = gid % 144;
    int py = pos / 12, px = pos % 12;
    const float* img = x + (size_t)b * 784;

    float patch[36];
#pragma unroll
    for (int r = 0; r < 6; ++r)
#pragma unroll
        for (int c = 0; c < 6; ++c)
            patch[r * 6 + c] = img[(2 * py + r) * 28 + 2 * px + c];

    float* outp = p1 + (size_t)b * 2880 + pos;
    for (int oc = 0; oc < 20; ++oc) {
        float bias = bsm[oc];
        float s00 = bias, s01 = bias, s10 = bias, s11 = bias;
        const float* w = &wsm[oc * 25];
#pragma unroll
        for (int ky = 0; ky < 5; ++ky)
#pragma unroll
            for (int kx = 0; kx < 5; ++kx) {
                float wv = w[ky * 5 + kx];
                s00 += patch[ky * 6 + kx] * wv;
                s01 += patch[ky * 6 + kx + 1] * wv;
                s10 += patch[(ky + 1) * 6 + kx] * wv;
                s11 += patch[(ky + 1) * 6 + kx + 1] * wv;
            }
        float m = fmaxf(fmaxf(fmaxf(trunc13(s00), 0.f), fmaxf(trunc13(s01), 0.f)),
                        fmaxf(fmaxf(trunc13(s10), 0.f), fmaxf(trunc13(s11), 0.f)));
        outp[oc * 144] = m;
    }
}

// ---------------------------------------------------------------------------
// K2: conv2 (20->50, 5x5) + bias + trunc + relu + 2x2 maxpool
// Block = 4 images (LDS, stride 2888 words to spread image bank groups),
// 256 thr = 4 waves. Wave w owns oc group [w*13, w*13+13) (52>=50, clamped).
// Lane = img*16 + pos. ic outer: 18 ds_read_b64 patch loads amortized over
// 13 oc; weight index is lane-invariant -> scalar s_load (free vs VALU).
// Per lane: 13*20*25*4 = 26000 FMA vs 360 ds_read_b64.
// ---------------------------------------------------------------------------
#define IMG_STRIDE 2888
__global__ __launch_bounds__(256) void k_conv2(const float* __restrict__ p1,
                                               const float* __restrict__ w2,
                                               const float* __restrict__ b2,
                                               float* __restrict__ p2) {
    __shared__ float in0[4 * IMG_STRIDE];
    int b0 = blockIdx.x * 4;
    int tid = threadIdx.x;
#pragma unroll
    for (int i4 = 0; i4 < 4; ++i4) {
        const float4* src = reinterpret_cast<const float4*>(p1 + (size_t)(b0 + i4) * 2880);
        float4* dst = reinterpret_cast<float4*>(&in0[i4 * IMG_STRIDE]);
        for (int t = tid; t < 720; t += 256) dst[t] = src[t];
    }
    __syncthreads();

    int wid  = tid >> 6;        // 0..3 -> oc group base wid*13
    int lane = tid & 63;
    int img  = lane >> 4;
    int pos  = lane & 15;
    int py = pos >> 2, px = pos & 3;
    const float* ibase = &in0[img * IMG_STRIDE + 2 * py * 12 + 2 * px];

    float acc[13][4];
#pragma unroll
    for (int j = 0; j < 13; ++j)
#pragma unroll
        for (int q = 0; q < 4; ++q) acc[j][q] = 0.f;

    for (int ic = 0; ic < 20; ++ic) {
        float patch[36];
        const float* ip = ibase + ic * 144;
#pragma unroll
        for (int r = 0; r < 6; ++r)
#pragma unroll
            for (int c = 0; c < 3; ++c) {
                float2 v = *reinterpret_cast<const float2*>(ip + r * 12 + 2 * c);
                patch[r * 6 + 2 * c]     = v.x;
                patch[r * 6 + 2 * c + 1] = v.y;
            }
#pragma unroll
        for (int j = 0; j < 13; ++j) {
            int oc  = wid * 13 + j;
            int ocw = (oc < 50) ? oc : 0;          // clamp: avoid OOB w2 reads
            const float* w = w2 + ocw * 500 + ic * 25;   // lane-invariant -> s_load
#pragma unroll
            for (int ky = 0; ky < 5; ++ky)
#pragma unroll
                for (int kx = 0; kx < 5; ++kx) {
                    float wv = w[ky * 5 + kx];
                    acc[j][0] += patch[ky * 6 + kx] * wv;
                    acc[j][1] += patch[ky * 6 + kx + 1] * wv;
                    acc[j][2] += patch[(ky + 1) * 6 + kx] * wv;
                    acc[j][3] += patch[(ky + 1) * 6 + kx + 1] * wv;
                }
        }
    }

#pragma unroll
    for (int j = 0; j < 13; ++j) {
        int oc = wid * 13 + j;
        if (oc < 50) {
            float bias = b2[oc];
            float m = fmaxf(fmaxf(fmaxf(trunc13(acc[j][0] + bias), 0.f),
                                  fmaxf(trunc13(acc[j][1] + bias), 0.f)),
                            fmaxf(fmaxf(trunc13(acc[j][2] + bias), 0.f),
                                  fmaxf(trunc13(acc[j][3] + bias), 0.f)));
            p2[(size_t)(b0 + img) * 800 + oc * 16 + pos] = m;
        }
    }
}

// ---------------------------------------------------------------------------
// K3: fc1  H = relu(trunc(A @ W^T + b))   A:[4096,800] W:[500,800] -> [4096,500]
// ---------------------------------------------------------------------------
__global__ __launch_bounds__(256) void k_fc1(const float* __restrict__ A,
                                             const float* __restrict__ W,
                                             const float* __restrict__ bias,
                                             float* __restrict__ H) {
    __shared__ __align__(16) float As[16][68];
    __shared__ __align__(16) float Ws[16][68];
    int tid = threadIdx.x;
    int tx = tid & 15;
    int ty = tid >> 4;
    int i0 = blockIdx.x * 64;
    int n0 = blockIdx.y * 64;
    int tm = tid & 15;
    int tn = tid >> 4;
    float acc[4][4] = {};

    for (int k0 = 0; k0 < 800; k0 += 16) {
#pragma unroll
        for (int q = 0; q < 4; ++q) {
            int row = ty + 16 * q;
            As[tx][row] = A[(size_t)(i0 + row) * 800 + k0 + tx];
            int n = n0 + row;
            Ws[tx][row] = (n < 500) ? W[(size_t)n * 800 + k0 + tx] : 0.f;
        }
        __syncthreads();
#pragma unroll
        for (int k = 0; k < 16; ++k) {
            float4 a = *reinterpret_cast<const float4*>(&As[k][tm * 4]);
            float4 w = *reinterpret_cast<const float4*>(&Ws[k][tn * 4]);
            float av[4] = {a.x, a.y, a.z, a.w};
            float wv[4] = {w.x, w.y, w.z, w.w};
#pragma unroll
            for (int r = 0; r < 4; ++r)
#pragma unroll
                for (int c = 0; c < 4; ++c)
                    acc[r][c] += av[r] * wv[c];
        }
        __syncthreads();
    }

#pragma unroll
    for (int r = 0; r < 4; ++r) {
        int i = i0 + tm * 4 + r;
#pragma unroll
        for (int c = 0; c < 4; ++c) {
            int n = n0 + tn * 4 + c;
            if (n < 500)
                H[(size_t)i * 500 + n] = fmaxf(trunc13(acc[r][c] + bias[n]), 0.f);
        }
    }
}

// ---------------------------------------------------------------------------
// K4: fc2 (500->10) + bias + trunc + log_softmax.  One wave per row.
// ---------------------------------------------------------------------------
__global__ __launch_bounds__(256) void k_fc2(const float* __restrict__ H,
                                             const float* __restrict__ W,
                                             const float* __restrict__ bias,
                                             float* __restrict__ out) {
    int wave = threadIdx.x >> 6;
    int lane = threadIdx.x & 63;
    int i = blockIdx.x * 4 + wave;
    const float* hrow = H + (size_t)i * 500;

    float p[10];
#pragma unroll
    for (int j = 0; j < 10; ++j) p[j] = 0.f;
    for (int k = lane; k < 500; k += 64) {
        float h = hrow[k];
#pragma unroll
        for (int j = 0; j < 10; ++j) p[j] += h * W[j * 500 + k];
    }
#pragma unroll
    for (int j = 0; j < 10; ++j)
#pragma unroll
        for (int off = 32; off; off >>= 1) p[j] += __shfl_xor(p[j], off, 64);

    if (lane == 0) {
        float z[10], m = -1e30f;
#pragma unroll
        for (int j = 0; j < 10; ++j) {
            z[j] = trunc13(p[j] + bias[j]);
            m = fmaxf(m, z[j]);
        }
        float s = 0.f;
#pragma unroll
        for (int j = 0; j < 10; ++j) s += expf(z[j] - m);
        float lse = m + logf(s);
#pragma unroll
        for (int j = 0; j < 10; ++j) out[(size_t)i * 10 + j] = z[j] - lse;
    }
}

// ---------------------------------------------------------------------------
extern "C" void kernel_launch(void* const* d_in, const int* in_sizes, int n_in,
                              void* d_out, int out_size, void* d_ws, size_t ws_size,
                              hipStream_t stream) {
    const float* x   = (const float*)d_in[0];
    const float* w1  = (const float*)d_in[1];
    const float* b1  = (const float*)d_in[2];
    const float* w2  = (const float*)d_in[3];
    const float* b2  = (const float*)d_in[4];
    const float* wf1 = (const float*)d_in[5];
    const float* bf1 = (const float*)d_in[6];
    const float* wf2 = (const float*)d_in[7];
    const float* bf2 = (const float*)d_in[8];
    float* out = (float*)d_out;

    float* p1 = (float*)d_ws;                        // 4096*2880
    float* p2 = p1 + (size_t)4096 * 2880;            // 4096*800
    float* h1 = p2 + (size_t)4096 * 800;             // 4096*500

    k_conv1<<<2304, 256, 0, stream>>>(x, w1, b1, p1);
    k_conv2<<<1024, 256, 0, stream>>>(p1, w2, b2, p2);
    dim3 g3(64, 8);
    k_fc1<<<g3, 256, 0, stream>>>(p2, wf1, bf1, h1);
    k_fc2<<<1024, 256, 0, stream>>>(h1, wf2, bf2, out);
}

// Round 3
// 343.797 us; speedup vs baseline: 1.2094x; 1.0939x over previous
//
#include <hip/hip_runtime.h>

// LeNet forward, BATCH=4096, all-fp32. trunc = zero low 13 mantissa bits.
// ws layout (floats): p1[4096*2880] | p2[4096*800] | h1[4096*500]  (~69 MB)

__device__ __forceinline__ float trunc13(float v) {
    return __int_as_float(__float_as_int(v) & (int)0xFFFFE000u);
}

// ---------------------------------------------------------------------------
// K1: conv1 (1->20, 5x5, VALID) + bias + trunc + relu + 2x2 maxpool
// ---------------------------------------------------------------------------
__global__ __launch_bounds__(256) void k_conv1(const float* __restrict__ x,
                                               const float* __restrict__ w1,
                                               const float* __restrict__ b1,
                                               float* __restrict__ p1) {
    __shared__ float wsm[500];
    __shared__ float bsm[20];
    int tid = threadIdx.x;
    for (int t = tid; t < 500; t += 256) wsm[t] = w1[t];
    if (tid < 20) bsm[tid] = b1[tid];
    __syncthreads();

    int gid = blockIdx.x * 256 + tid;   // 4096*144 = 589824 = 2304*256 exact
    int b   = gid / 144;
    int pos = gid % 144;
    int py = pos / 12, px = pos % 12;
    const float* img = x + (size_t)b * 784;

    float patch[36];
#pragma unroll
    for (int r = 0; r < 6; ++r)
#pragma unroll
        for (int c = 0; c < 6; ++c)
            patch[r * 6 + c] = img[(2 * py + r) * 28 + 2 * px + c];

    float* outp = p1 + (size_t)b * 2880 + pos;
    for (int oc = 0; oc < 20; ++oc) {
        float bias = bsm[oc];
        float s00 = bias, s01 = bias, s10 = bias, s11 = bias;
        const float* w = &wsm[oc * 25];
#pragma unroll
        for (int ky = 0; ky < 5; ++ky)
#pragma unroll
            for (int kx = 0; kx < 5; ++kx) {
                float wv = w[ky * 5 + kx];
                s00 += patch[ky * 6 + kx] * wv;
                s01 += patch[ky * 6 + kx + 1] * wv;
                s10 += patch[(ky + 1) * 6 + kx] * wv;
                s11 += patch[(ky + 1) * 6 + kx + 1] * wv;
            }
        float m = fmaxf(fmaxf(fmaxf(trunc13(s00), 0.f), fmaxf(trunc13(s01), 0.f)),
                        fmaxf(fmaxf(trunc13(s10), 0.f), fmaxf(trunc13(s11), 0.f)));
        outp[oc * 144] = m;
    }
}

// ---------------------------------------------------------------------------
// K2: conv2 (20->50, 5x5) + bias + trunc + relu + 2x2 maxpool
// Block = 4 images in LDS, 4 waves; wave w owns oc in [13w, 13w+13).
// Weight offset forced wave-uniform via readfirstlane -> scalar s_load path;
// FMAs consume weights as the SGPR operand (no VMEM, no VGPR cost).
// ---------------------------------------------------------------------------
#define IMG_STRIDE 2888
__global__ __launch_bounds__(256) void k_conv2(const float* __restrict__ p1,
                                               const float* __restrict__ w2,
                                               const float* __restrict__ b2,
                                               float* __restrict__ p2) {
    __shared__ float in0[4 * IMG_STRIDE];
    int b0 = blockIdx.x * 4;
    int tid = threadIdx.x;
#pragma unroll
    for (int i4 = 0; i4 < 4; ++i4) {
        const float4* src = reinterpret_cast<const float4*>(p1 + (size_t)(b0 + i4) * 2880);
        float4* dst = reinterpret_cast<float4*>(&in0[i4 * IMG_STRIDE]);
        for (int t = tid; t < 720; t += 256) dst[t] = src[t];
    }
    __syncthreads();

    int wid  = tid >> 6;        // wave id -> oc group base wid*13
    int lane = tid & 63;
    int img  = lane >> 4;
    int pos  = lane & 15;
    int py = pos >> 2, px = pos & 3;
    const float* ibase = &in0[img * IMG_STRIDE + 2 * py * 12 + 2 * px];

    float acc[13][4];
#pragma unroll
    for (int j = 0; j < 13; ++j)
#pragma unroll
        for (int q = 0; q < 4; ++q) acc[j][q] = 0.f;

    for (int ic = 0; ic < 20; ++ic) {
        float patch[36];
        const float* ip = ibase + ic * 144;
#pragma unroll
        for (int r = 0; r < 6; ++r)
#pragma unroll
            for (int c = 0; c < 3; ++c) {
                float2 v = *reinterpret_cast<const float2*>(ip + r * 12 + 2 * c);
                patch[r * 6 + 2 * c]     = v.x;
                patch[r * 6 + 2 * c + 1] = v.y;
            }
#pragma unroll
        for (int j = 0; j < 13; ++j) {
            int oc  = wid * 13 + j;
            int ocw = (oc < 50) ? oc : 0;          // clamp: avoid OOB w2 reads
            // Force wave-uniform offset into an SGPR -> scalar-cache s_loads.
            int woff = __builtin_amdgcn_readfirstlane(ocw * 500 + ic * 25);
            const float* w = w2 + woff;
#pragma unroll
            for (int ky = 0; ky < 5; ++ky)
#pragma unroll
                for (int kx = 0; kx < 5; ++kx) {
                    float wv = w[ky * 5 + kx];
                    acc[j][0] += patch[ky * 6 + kx] * wv;
                    acc[j][1] += patch[ky * 6 + kx + 1] * wv;
                    acc[j][2] += patch[(ky + 1) * 6 + kx] * wv;
                    acc[j][3] += patch[(ky + 1) * 6 + kx + 1] * wv;
                }
        }
    }

#pragma unroll
    for (int j = 0; j < 13; ++j) {
        int oc = wid * 13 + j;
        if (oc < 50) {
            float bias = b2[oc];
            float m = fmaxf(fmaxf(fmaxf(trunc13(acc[j][0] + bias), 0.f),
                                  fmaxf(trunc13(acc[j][1] + bias), 0.f)),
                            fmaxf(fmaxf(trunc13(acc[j][2] + bias), 0.f),
                                  fmaxf(trunc13(acc[j][3] + bias), 0.f)));
            p2[(size_t)(b0 + img) * 800 + oc * 16 + pos] = m;
        }
    }
}

// ---------------------------------------------------------------------------
// K3: fc1  H = relu(trunc(A @ W^T + b))   A:[4096,800] W:[500,800] -> [4096,500]
// ---------------------------------------------------------------------------
__global__ __launch_bounds__(256) void k_fc1(const float* __restrict__ A,
                                             const float* __restrict__ W,
                                             const float* __restrict__ bias,
                                             float* __restrict__ H) {
    __shared__ __align__(16) float As[16][68];
    __shared__ __align__(16) float Ws[16][68];
    int tid = threadIdx.x;
    int tx = tid & 15;
    int ty = tid >> 4;
    int i0 = blockIdx.x * 64;
    int n0 = blockIdx.y * 64;
    int tm = tid & 15;
    int tn = tid >> 4;
    float acc[4][4] = {};

    for (int k0 = 0; k0 < 800; k0 += 16) {
#pragma unroll
        for (int q = 0; q < 4; ++q) {
            int row = ty + 16 * q;
            As[tx][row] = A[(size_t)(i0 + row) * 800 + k0 + tx];
            int n = n0 + row;
            Ws[tx][row] = (n < 500) ? W[(size_t)n * 800 + k0 + tx] : 0.f;
        }
        __syncthreads();
#pragma unroll
        for (int k = 0; k < 16; ++k) {
            float4 a = *reinterpret_cast<const float4*>(&As[k][tm * 4]);
            float4 w = *reinterpret_cast<const float4*>(&Ws[k][tn * 4]);
            float av[4] = {a.x, a.y, a.z, a.w};
            float wv[4] = {w.x, w.y, w.z, w.w};
#pragma unroll
            for (int r = 0; r < 4; ++r)
#pragma unroll
                for (int c = 0; c < 4; ++c)
                    acc[r][c] += av[r] * wv[c];
        }
        __syncthreads();
    }

#pragma unroll
    for (int r = 0; r < 4; ++r) {
        int i = i0 + tm * 4 + r;
#pragma unroll
        for (int c = 0; c < 4; ++c) {
            int n = n0 + tn * 4 + c;
            if (n < 500)
                H[(size_t)i * 500 + n] = fmaxf(trunc13(acc[r][c] + bias[n]), 0.f);
        }
    }
}

// ---------------------------------------------------------------------------
// K4: fc2 (500->10) + bias + trunc + log_softmax.  One wave per row.
// ---------------------------------------------------------------------------
__global__ __launch_bounds__(256) void k_fc2(const float* __restrict__ H,
                                             const float* __restrict__ W,
                                             const float* __restrict__ bias,
                                             float* __restrict__ out) {
    int wave = threadIdx.x >> 6;
    int lane = threadIdx.x & 63;
    int i = blockIdx.x * 4 + wave;
    const float* hrow = H + (size_t)i * 500;

    float p[10];
#pragma unroll
    for (int j = 0; j < 10; ++j) p[j] = 0.f;
    for (int k = lane; k < 500; k += 64) {
        float h = hrow[k];
#pragma unroll
        for (int j = 0; j < 10; ++j) p[j] += h * W[j * 500 + k];
    }
#pragma unroll
    for (int j = 0; j < 10; ++j)
#pragma unroll
        for (int off = 32; off; off >>= 1) p[j] += __shfl_xor(p[j], off, 64);

    if (lane == 0) {
        float z[10], m = -1e30f;
#pragma unroll
        for (int j = 0; j < 10; ++j) {
            z[j] = trunc13(p[j] + bias[j]);
            m = fmaxf(m, z[j]);
        }
        float s = 0.f;
#pragma unroll
        for (int j = 0; j < 10; ++j) s += expf(z[j] - m);
        float lse = m + logf(s);
#pragma unroll
        for (int j = 0; j < 10; ++j) out[(size_t)i * 10 + j] = z[j] - lse;
    }
}

// ---------------------------------------------------------------------------
extern "C" void kernel_launch(void* const* d_in, const int* in_sizes, int n_in,
                              void* d_out, int out_size, void* d_ws, size_t ws_size,
                              hipStream_t stream) {
    const float* x   = (const float*)d_in[0];
    const float* w1  = (const float*)d_in[1];
    const float* b1  = (const float*)d_in[2];
    const float* w2  = (const float*)d_in[3];
    const float* b2  = (const float*)d_in[4];
    const float* wf1 = (const float*)d_in[5];
    const float* bf1 = (const float*)d_in[6];
    const float* wf2 = (const float*)d_in[7];
    const float* bf2 = (const float*)d_in[8];
    float* out = (float*)d_out;

    float* p1 = (float*)d_ws;                        // 4096*2880
    float* p2 = p1 + (size_t)4096 * 2880;            // 4096*800
    float* h1 = p2 + (size_t)4096 * 800;             // 4096*500

    k_conv1<<<2304, 256, 0, stream>>>(x, w1, b1, p1);
    k_conv2<<<1024, 256, 0, stream>>>(p1, w2, b2, p2);
    dim3 g3(64, 8);
    k_fc1<<<g3, 256, 0, stream>>>(p2, wf1, bf1, h1);
    k_fc2<<<1024, 256, 0, stream>>>(h1, wf2, bf2, out);
}